// Round 2
// baseline (773.341 us; speedup 1.0000x reference)
//
#include <hip/hip_runtime.h>
#include <hip/hip_fp16.h>

#define N_NODES 50000
#define N_EDGES 500000
#define NCLS 40
#define NBLK ((N_NODES + 255) / 256)   // 196
#define EBLK ((N_EDGES + 255) / 256)   // 1954

__device__ inline unsigned pack2(float a, float b) {
    __half2 h = __floats2half2_rn(a, b);
    return *(unsigned*)&h;
}
__device__ inline float2 unpack2(unsigned u) {
    __half2 h = *(__half2*)&u;
    return __half22float2(h);
}

// ---- dual histogram: in-degree (dst) and out-degree (src) ----
__global__ void hist2_k(const int* __restrict__ src, const int* __restrict__ dst,
                        int* __restrict__ cntD, int* __restrict__ cntS) {
    int e = blockIdx.x * 256 + threadIdx.x;
    if (e < N_EDGES) {
        atomicAdd(&cntD[dst[e]], 1);
        atomicAdd(&cntS[src[e]], 1);
    }
}

// ---- single-kernel scan: per-block scan + publish + parallel lookback ----
__global__ __launch_bounds__(256) void scan_k(const int* __restrict__ cnt,
                                              int* __restrict__ start,
                                              int* __restrict__ cursor,
                                              volatile int* __restrict__ bflag,
                                              volatile int* __restrict__ bval) {
    __shared__ int ls[256];
    __shared__ int sbase;
    __shared__ int ok_all;
    int b = blockIdx.x, t = threadIdx.x;
    int n = b * 256 + t;
    int v = (n < N_NODES) ? cnt[n] : 0;
    ls[t] = v;
    __syncthreads();
#pragma unroll
    for (int off = 1; off < 256; off <<= 1) {
        int u = (t >= off) ? ls[t - off] : 0;
        __syncthreads();
        ls[t] += u;
        __syncthreads();
    }
    int incl = ls[t];
    int total = ls[255];
    __syncthreads();

    if (t == 0) {
        bval[b] = total;
        __threadfence();
        bflag[b] = 1;
    }

    if (b > 0) {
        for (;;) {
            int f = (t < b) ? bflag[t] : 1;
            if (t == 0) ok_all = 1;
            __syncthreads();
            if (!f) ok_all = 0;
            __syncthreads();
            if (ok_all) break;
        }
        __threadfence();
        int pv = (t < b) ? bval[t] : 0;
        ls[t] = pv;
        __syncthreads();
#pragma unroll
        for (int off = 128; off > 0; off >>= 1) {
            if (t < off) ls[t] += ls[t + off];
            __syncthreads();
        }
        if (t == 0) sbase = ls[0];
        __syncthreads();
    } else {
        if (t == 0) sbase = 0;
        __syncthreads();
    }

    int excl = sbase + incl - v;
    if (n < N_NODES) { start[n] = excl; cursor[n] = excl; }
    if (n == 0) start[N_NODES] = N_EDGES;
}

// ---- scatter: src-sorted records carrying dst-sorted position + packed e + src ----
__global__ void scatter_k(const int* __restrict__ src, const int* __restrict__ dst,
                          const float* __restrict__ ef,
                          int* __restrict__ cursorD, int* __restrict__ cursorS,
                          uint4* __restrict__ recS0, uint4* __restrict__ recS1) {
    int e = blockIdx.x * 256 + threadIdx.x;
    if (e < N_EDGES) {
        int d = dst[e], s = src[e];
        int pD = atomicAdd(&cursorD[d], 1);
        int pS = atomicAdd(&cursorS[s], 1);
        float4 f0 = ((const float4*)ef)[e];
        float4 f1 = ((const float4*)ef)[N_EDGES + e];
        recS0[pS] = make_uint4((unsigned)pD, pack2(f0.x, f0.y), pack2(f0.z, f0.w), (unsigned)s);
        recS1[pS] = make_uint4((unsigned)pD, pack2(f1.x, f1.y), pack2(f1.z, f1.w), (unsigned)s);
    }
}

// ---- per-edge message from in-LDS y fragments ----
__device__ inline float4 msg_from(uint4 rec,
                                  float2 a0, float2 a1, float2 b0, float2 b1,
                                  float2 c0, float2 c1, float2 d0, float2 d1,
                                  float4 bias) {
    float2 e01 = unpack2(rec.y);
    float2 e23 = unpack2(rec.z);
    float4 z = bias;
    z.x = fmaf(e01.x, a0.x, z.x); z.y = fmaf(e01.x, a0.y, z.y);
    z.z = fmaf(e01.x, a1.x, z.z); z.w = fmaf(e01.x, a1.y, z.w);
    z.x = fmaf(e01.y, b0.x, z.x); z.y = fmaf(e01.y, b0.y, z.y);
    z.z = fmaf(e01.y, b1.x, z.z); z.w = fmaf(e01.y, b1.y, z.w);
    z.x = fmaf(e23.x, c0.x, z.x); z.y = fmaf(e23.x, c0.y, z.y);
    z.z = fmaf(e23.x, c1.x, z.z); z.w = fmaf(e23.x, c1.y, z.w);
    z.x = fmaf(e23.y, d0.x, z.x); z.y = fmaf(e23.y, d0.y, z.y);
    z.z = fmaf(e23.y, d1.x, z.z); z.w = fmaf(e23.y, d1.y, z.w);
    z.x = fmaxf(z.x, 0.f); z.y = fmaxf(z.y, 0.f);
    z.z = fmaxf(z.z, 0.f); z.w = fmaxf(z.w, 0.f);
    return z;
}

// ---- fused transform + message kernel: 64 src nodes per block ----
// phase A: per k-slice GEMM (h read from global/L1, W staged in LDS) -> half y in LDS
// phase B: edge-balanced walk of the block's contiguous src-sorted out-edge range,
//          write fp32 messages to mbuf[posD]
// LDS: 16KB sW + 32KB yL = 48KB -> 3 blocks/CU
__global__ __launch_bounds__(256) void fused_k(const float* __restrict__ hin,
                                               const float* __restrict__ W,
                                               const float* __restrict__ b,
                                               const uint4* __restrict__ recS,
                                               const int* __restrict__ startS,
                                               float* __restrict__ mbuf) {
    __shared__ float sW[64 * 64];        // one k-slice of W
    __shared__ unsigned yL[64 * 128];    // half-packed y: [node][k*32 + h/2]
    int t = threadIdx.x;
    int n0 = blockIdx.x * 64;

    // ---- phase A: per k-slice GEMM into yL ----
    int nl2 = t & 31;
    int cg = t >> 5;                  // 0..7 col-groups of 8 cols
    int hc0 = cg * 8;
    int nA = n0 + nl2, nB = nA + 32;
    bool vA = nA < N_NODES, vB = nB < N_NODES;
    const float4* h4A = (const float4*)hin + (size_t)nA * 16;
    const float4* h4B = (const float4*)hin + (size_t)nB * 16;
    const float4 zf4 = make_float4(0.f, 0.f, 0.f, 0.f);

    for (int k = 0; k < 4; ++k) {
        const float4* W4 = (const float4*)(W + (size_t)k * 4096);
        float4* sW4 = (float4*)sW;
#pragma unroll
        for (int i = 0; i < 4; ++i) sW4[t + 256 * i] = W4[t + 256 * i];
        __syncthreads();
        float acc0[8], acc1[8];
#pragma unroll
        for (int j = 0; j < 8; ++j) { acc0[j] = 0.f; acc1[j] = 0.f; }
#pragma unroll 2
        for (int d4 = 0; d4 < 16; ++d4) {
            float4 hA = vA ? h4A[d4] : zf4;
            float4 hB = vB ? h4B[d4] : zf4;
            int d = d4 * 4;
#pragma unroll
            for (int dd = 0; dd < 4; ++dd) {
                float a0 = (dd == 0) ? hA.x : (dd == 1) ? hA.y : (dd == 2) ? hA.z : hA.w;
                float a1 = (dd == 0) ? hB.x : (dd == 1) ? hB.y : (dd == 2) ? hB.z : hB.w;
                const float4* wr4 = (const float4*)&sW[(d + dd) * 64 + hc0];
                float4 wa = wr4[0], wb = wr4[1];
                acc0[0] = fmaf(a0, wa.x, acc0[0]); acc1[0] = fmaf(a1, wa.x, acc1[0]);
                acc0[1] = fmaf(a0, wa.y, acc0[1]); acc1[1] = fmaf(a1, wa.y, acc1[1]);
                acc0[2] = fmaf(a0, wa.z, acc0[2]); acc1[2] = fmaf(a1, wa.z, acc1[2]);
                acc0[3] = fmaf(a0, wa.w, acc0[3]); acc1[3] = fmaf(a1, wa.w, acc1[3]);
                acc0[4] = fmaf(a0, wb.x, acc0[4]); acc1[4] = fmaf(a1, wb.x, acc1[4]);
                acc0[5] = fmaf(a0, wb.y, acc0[5]); acc1[5] = fmaf(a1, wb.y, acc1[5]);
                acc0[6] = fmaf(a0, wb.z, acc0[6]); acc1[6] = fmaf(a1, wb.z, acc1[6]);
                acc0[7] = fmaf(a0, wb.w, acc0[7]); acc1[7] = fmaf(a1, wb.w, acc1[7]);
            }
        }
        unsigned* y0 = &yL[nl2 * 128 + k * 32 + cg * 4];
        unsigned* y1 = &yL[(nl2 + 32) * 128 + k * 32 + cg * 4];
#pragma unroll
        for (int j = 0; j < 4; ++j) {
            y0[j] = pack2(acc0[2 * j], acc0[2 * j + 1]);
            y1[j] = pack2(acc1[2 * j], acc1[2 * j + 1]);
        }
        __syncthreads();              // protect sW restage / final yL visibility
    }

    // ---- phase B: edge-balanced message generation ----
    int nEnd = (n0 + 64 < N_NODES) ? n0 + 64 : N_NODES;
    int e0 = startS[n0];
    int e1 = startS[nEnd];
    int g = t >> 4;
    int lane = t & 15;
    float4 bias = ((const float4*)b)[lane];
    float4* mb4 = (float4*)mbuf;

    int e = e0 + g;
    for (; e + 16 < e1; e += 32) {
        uint4 rA = recS[e];
        uint4 rB = recS[e + 16];
        int nlA = (int)rA.w - n0;
        int nlB = (int)rB.w - n0;
        const unsigned* yA = &yL[nlA * 128 + 2 * lane];
        const unsigned* yB = &yL[nlB * 128 + 2 * lane];
        uint2 qA0 = *(const uint2*)&yA[0];
        uint2 qA1 = *(const uint2*)&yA[32];
        uint2 qA2 = *(const uint2*)&yA[64];
        uint2 qA3 = *(const uint2*)&yA[96];
        uint2 qB0 = *(const uint2*)&yB[0];
        uint2 qB1 = *(const uint2*)&yB[32];
        uint2 qB2 = *(const uint2*)&yB[64];
        uint2 qB3 = *(const uint2*)&yB[96];
        float4 mA = msg_from(rA, unpack2(qA0.x), unpack2(qA0.y), unpack2(qA1.x), unpack2(qA1.y),
                             unpack2(qA2.x), unpack2(qA2.y), unpack2(qA3.x), unpack2(qA3.y), bias);
        float4 mB = msg_from(rB, unpack2(qB0.x), unpack2(qB0.y), unpack2(qB1.x), unpack2(qB1.y),
                             unpack2(qB2.x), unpack2(qB2.y), unpack2(qB3.x), unpack2(qB3.y), bias);
        mb4[(size_t)rA.x * 16 + lane] = mA;
        mb4[(size_t)rB.x * 16 + lane] = mB;
    }
    if (e < e1) {
        uint4 rA = recS[e];
        int nlA = (int)rA.w - n0;
        const unsigned* yA = &yL[nlA * 128 + 2 * lane];
        uint2 qA0 = *(const uint2*)&yA[0];
        uint2 qA1 = *(const uint2*)&yA[32];
        uint2 qA2 = *(const uint2*)&yA[64];
        uint2 qA3 = *(const uint2*)&yA[96];
        float4 mA = msg_from(rA, unpack2(qA0.x), unpack2(qA0.y), unpack2(qA1.x), unpack2(qA1.y),
                             unpack2(qA2.x), unpack2(qA2.y), unpack2(qA3.x), unpack2(qA3.y), bias);
        mb4[(size_t)rA.x * 16 + lane] = mA;
    }
}

// ---- streaming segment mean+relu over fp32 messages ----
__device__ inline float4 seg_mean_relu(const float* __restrict__ mbuf,
                                       int s0, int c, int lane) {
    const float4* mb = (const float4*)mbuf + (size_t)s0 * 16 + lane;
    float4 p0 = make_float4(0.f, 0.f, 0.f, 0.f);
    float4 p1 = p0, p2 = p0, p3 = p0;
    int i = 0;
    for (; i + 4 <= c; i += 4) {
        float4 v0 = mb[(size_t)(i + 0) * 16];
        float4 v1 = mb[(size_t)(i + 1) * 16];
        float4 v2 = mb[(size_t)(i + 2) * 16];
        float4 v3 = mb[(size_t)(i + 3) * 16];
        p0.x += v0.x; p0.y += v0.y; p0.z += v0.z; p0.w += v0.w;
        p1.x += v1.x; p1.y += v1.y; p1.z += v1.z; p1.w += v1.w;
        p2.x += v2.x; p2.y += v2.y; p2.z += v2.z; p2.w += v2.w;
        p3.x += v3.x; p3.y += v3.y; p3.z += v3.z; p3.w += v3.w;
    }
    for (; i < c; ++i) {
        float4 v = mb[(size_t)i * 16];
        p0.x += v.x; p0.y += v.y; p0.z += v.z; p0.w += v.w;
    }
    float inv = 1.0f / (float)(c > 1 ? c : 1);
    float4 r;
    r.x = fmaxf((p0.x + p1.x + p2.x + p3.x) * inv, 0.f);
    r.y = fmaxf((p0.y + p1.y + p2.y + p3.y) * inv, 0.f);
    r.z = fmaxf((p0.z + p1.z + p2.z + p3.z) * inv, 0.f);
    r.w = fmaxf((p0.w + p1.w + p2.w + p3.w) * inv, 0.f);
    return r;
}

// ---- layer-0 aggregate: mbuf -> hbuf (fp32) ----
__global__ __launch_bounds__(256) void agg_k(const float* __restrict__ mbuf,
                                             const int* __restrict__ startD,
                                             const int* __restrict__ cntD,
                                             float* __restrict__ hout) {
    int t = blockIdx.x * 256 + threadIdx.x;
    int g = t >> 4;
    int lane = t & 15;
    float4 r = seg_mean_relu(mbuf, startD[g], cntD[g], lane);
    ((float4*)hout)[(size_t)g * 16 + lane] = r;
}

// ---- layer-1 aggregate fused with final fc (block = 16 nodes) ----
__global__ __launch_bounds__(256) void agg_fc_k(const float* __restrict__ mbuf,
                                                const int* __restrict__ startD,
                                                const int* __restrict__ cntD,
                                                const float* __restrict__ Wfc,
                                                const float* __restrict__ bfc,
                                                float* __restrict__ out) {
    __shared__ float sh_h[16 * 65];
    __shared__ float sWfcT[NCLS * 65];   // transposed, padded
    __shared__ float sbfc[NCLS];
    int t = threadIdx.x;

    for (int i = t; i < 64 * NCLS; i += 256) {
        int j = i / NCLS;
        int c = i - j * NCLS;
        sWfcT[c * 65 + j] = Wfc[i];
    }
    if (t < NCLS) sbfc[t] = bfc[t];

    int nl = t >> 4;
    int lane = t & 15;
    int g = blockIdx.x * 16 + nl;        // grid exact: 3125*16 = 50000

    float4 r = seg_mean_relu(mbuf, startD[g], cntD[g], lane);
    sh_h[nl * 65 + lane * 4 + 0] = r.x;
    sh_h[nl * 65 + lane * 4 + 1] = r.y;
    sh_h[nl * 65 + lane * 4 + 2] = r.z;
    sh_h[nl * 65 + lane * 4 + 3] = r.w;
    __syncthreads();

    for (int item = t; item < 16 * NCLS; item += 256) {
        int rn = item / NCLS;
        int c = item - rn * NCLS;
        float acc = sbfc[c];
        const float* hr = &sh_h[rn * 65];
        const float* wc = &sWfcT[c * 65];
#pragma unroll
        for (int j = 0; j < 64; ++j) acc = fmaf(hr[j], wc[j], acc);
        out[(size_t)(blockIdx.x * 16 + rn) * NCLS + c] = acc;
    }
}

extern "C" void kernel_launch(void* const* d_in, const int* in_sizes, int n_in,
                              void* d_out, int out_size, void* d_ws, size_t ws_size,
                              hipStream_t stream) {
    const float* nf  = (const float*)d_in[0];
    const float* ef  = (const float*)d_in[1];
    const int*   src = (const int*)d_in[2];
    const int*   dst = (const int*)d_in[3];
    const float* W0  = (const float*)d_in[4];
    const float* b0  = (const float*)d_in[5];
    const float* W1  = (const float*)d_in[6];
    const float* b1  = (const float*)d_in[7];
    const float* Wfc = (const float*)d_in[8];
    const float* bfc = (const float*)d_in[9];
    float* out = (float*)d_out;

    char* ws = (char*)d_ws;
    size_t off = 0;
    auto alloc = [&](size_t bytes) -> void* {
        void* p = ws + off;
        off = (off + bytes + 255) & ~(size_t)255;
        return p;
    };
    // zeroed region: cntD | cntS | bflagD | bvalD | bflagS | bvalS
    int* zbuf    = (int*)alloc((size_t)(2 * 50176 + 1024) * 4);
    int* cntD    = zbuf;
    int* cntS    = zbuf + 50176;
    int* bflagD  = zbuf + 2 * 50176;
    int* bvalD   = bflagD + 256;
    int* bflagS  = bvalD + 256;
    int* bvalS   = bflagS + 256;
    int* startD  = (int*)alloc((size_t)(N_NODES + 4) * 4);
    int* cursorD = (int*)alloc((size_t)N_NODES * 4);
    int* startS  = (int*)alloc((size_t)(N_NODES + 4) * 4);
    int* cursorS = (int*)alloc((size_t)N_NODES * 4);
    uint4* recS0 = (uint4*)alloc((size_t)N_EDGES * 16);
    uint4* recS1 = (uint4*)alloc((size_t)N_EDGES * 16);
    float* mbuf  = (float*)alloc((size_t)N_EDGES * 64 * 4);   // 122 MiB fp32 messages
    float* hbuf  = (float*)alloc((size_t)N_NODES * 64 * 4);

    hipMemsetAsync(zbuf, 0, (size_t)(2 * 50176 + 1024) * 4, stream);

    hist2_k<<<EBLK, 256, 0, stream>>>(src, dst, cntD, cntS);
    scan_k<<<NBLK, 256, 0, stream>>>(cntD, startD, cursorD, bflagD, bvalD);
    scan_k<<<NBLK, 256, 0, stream>>>(cntS, startS, cursorS, bflagS, bvalS);
    scatter_k<<<EBLK, 256, 0, stream>>>(src, dst, ef, cursorD, cursorS, recS0, recS1);

    int fgrid = (N_NODES + 63) / 64;   // 782
    int agrid = N_NODES / 16;          // 3125, exact

    // layer 0: fused transform+message, then streaming aggregate
    fused_k<<<fgrid, 256, 0, stream>>>(nf, W0, b0, recS0, startS, mbuf);
    agg_k<<<agrid, 256, 0, stream>>>(mbuf, startD, cntD, hbuf);

    // layer 1: fused transform+message, then aggregate + classifier
    fused_k<<<fgrid, 256, 0, stream>>>(hbuf, W1, b1, recS1, startS, mbuf);
    agg_fc_k<<<agrid, 256, 0, stream>>>(mbuf, startD, cntD, Wfc, bfc, out);
}

// Round 3
// 375.898 us; speedup vs baseline: 2.0573x; 2.0573x over previous
//
#include <hip/hip_runtime.h>
#include <hip/hip_fp16.h>

#define N_NODES 50000
#define N_EDGES 500000
#define DIM 64
#define KDIM 4
#define HID 64
#define NCLS 40
#define NBLK ((N_NODES + 255) / 256)   // 196
#define EBLK ((N_EDGES + 255) / 256)   // 1954

__device__ inline unsigned pack2(float a, float b) {
    __half2 h = __floats2half2_rn(a, b);
    return *(unsigned*)&h;
}
__device__ inline float2 unpack2(unsigned u) {
    __half2 h = *(__half2*)&u;
    return __half22float2(h);
}

// ---- histogram of dst (in-degree) ----
__global__ void hist_k(const int* __restrict__ dst, int* __restrict__ cnt) {
    int e = blockIdx.x * 256 + threadIdx.x;
    if (e < N_EDGES) atomicAdd(&cnt[dst[e]], 1);
}

// ---- single-kernel scan: per-block scan + publish + parallel lookback ----
__global__ __launch_bounds__(256) void scan_k(const int* __restrict__ cnt,
                                              int* __restrict__ start,
                                              int* __restrict__ cursor,
                                              volatile int* __restrict__ bflag,
                                              volatile int* __restrict__ bval) {
    __shared__ int ls[256];
    __shared__ int sbase;
    __shared__ int ok_all;
    int b = blockIdx.x, t = threadIdx.x;
    int n = b * 256 + t;
    int v = (n < N_NODES) ? cnt[n] : 0;
    ls[t] = v;
    __syncthreads();
#pragma unroll
    for (int off = 1; off < 256; off <<= 1) {
        int u = (t >= off) ? ls[t - off] : 0;
        __syncthreads();
        ls[t] += u;
        __syncthreads();
    }
    int incl = ls[t];
    int total = ls[255];
    __syncthreads();

    if (t == 0) {
        bval[b] = total;
        __threadfence();
        bflag[b] = 1;
    }

    if (b > 0) {
        for (;;) {
            int f = (t < b) ? bflag[t] : 1;
            if (t == 0) ok_all = 1;
            __syncthreads();
            if (!f) ok_all = 0;
            __syncthreads();
            if (ok_all) break;
        }
        __threadfence();
        int pv = (t < b) ? bval[t] : 0;
        ls[t] = pv;
        __syncthreads();
#pragma unroll
        for (int off = 128; off > 0; off >>= 1) {
            if (t < off) ls[t] += ls[t + off];
            __syncthreads();
        }
        if (t == 0) sbase = ls[0];
        __syncthreads();
    } else {
        if (t == 0) sbase = 0;
        __syncthreads();
    }

    int excl = sbase + incl - v;
    if (n < N_NODES) { start[n] = excl; cursor[n] = excl; }
    if (n == 0) start[N_NODES] = N_EDGES;
}

// ---- counting-sort scatter: de-interleaved 16B records per layer ----
__global__ void scatter_k(const int* __restrict__ src, const int* __restrict__ dst,
                          const float* __restrict__ ef, int* __restrict__ cursor,
                          uint4* __restrict__ recA, uint4* __restrict__ recB) {
    int e = blockIdx.x * 256 + threadIdx.x;
    if (e < N_EDGES) {
        int d = dst[e];
        int pos = atomicAdd(&cursor[d], 1);
        int sn = src[e];
        float4 f0 = ((const float4*)ef)[e];
        float4 f1 = ((const float4*)ef)[N_EDGES + e];
        recA[pos] = make_uint4((unsigned)sn, pack2(f0.x, f0.y), pack2(f0.z, f0.w), 0u);
        recB[pos] = make_uint4((unsigned)sn, pack2(f1.x, f1.y), pack2(f1.z, f1.w), 0u);
    }
}

// ---- node transform, split-k: blockIdx.y = kpair (k in {2*kpair, 2*kpair+1}) ----
// 64 nodes/block, 32KB W-slice + 16.6KB h-tile = 48.9KB LDS -> 3 blocks/CU
__global__ __launch_bounds__(256) void transform_k(const float* __restrict__ hin,
                                                   const float* __restrict__ W,
                                                   unsigned* __restrict__ y) {
    __shared__ float sW[2 * 64 * 64];      // 32 KB: two k-slices
    __shared__ float sh[64 * 65];          // 16.6 KB
    int t = threadIdx.x;
    int kpair = blockIdx.y;

    // stage W slice: 8192 floats = 2048 float4 / 256 threads = 8 each
    const float4* W4 = (const float4*)(W + (size_t)kpair * 2 * 4096);
    float4* sW4 = (float4*)sW;
#pragma unroll
    for (int i = 0; i < 8; ++i) sW4[t + 256 * i] = W4[t + 256 * i];

    int n0 = blockIdx.x * 64;
    // stage h tile: 64 nodes x 16 float4 = 1024 float4 -> 4 per thread
#pragma unroll
    for (int i = 0; i < 4; ++i) {
        int idx = t + 256 * i;        // 0..1023
        int nl = idx >> 4;            // 0..63
        int dg = idx & 15;
        int n = n0 + nl;
        float4 v = make_float4(0.f, 0.f, 0.f, 0.f);
        if (n < N_NODES) v = ((const float4*)hin)[(size_t)n * 16 + dg];
        sh[nl * 65 + dg * 4 + 0] = v.x;
        sh[nl * 65 + dg * 4 + 1] = v.y;
        sh[nl * 65 + dg * 4 + 2] = v.z;
        sh[nl * 65 + dg * 4 + 3] = v.w;
    }
    __syncthreads();

    // 256 threads = 8 col-groups (16 cols each over the 128 cols of this kpair)
    // x 32 node-slots; each slot handles nodes nl and nl+32
    int nl = t & 31;
    int cg = t >> 5;                  // 0..7
    int k_local = cg >> 2;            // 0..1
    int hc0 = (cg & 3) * 16;

    float acc0[16], acc1[16];
#pragma unroll
    for (int j = 0; j < 16; ++j) { acc0[j] = 0.f; acc1[j] = 0.f; }

    for (int d = 0; d < 64; ++d) {
        float a0 = sh[nl * 65 + d];
        float a1 = sh[(nl + 32) * 65 + d];
        const float* wr = &sW[k_local * 4096 + d * 64 + hc0];
#pragma unroll
        for (int j = 0; j < 16; ++j) {
            float w = wr[j];
            acc0[j] = fmaf(a0, w, acc0[j]);
            acc1[j] = fmaf(a1, w, acc1[j]);
        }
    }

    int n_a = n0 + nl, n_b = n0 + nl + 32;
    int cbase = (kpair * 2 + k_local) * 64 + hc0;
    if (n_a < N_NODES) {
        uint4* o = (uint4*)(y + ((size_t)n_a * 256 + cbase) / 2);
        o[0] = make_uint4(pack2(acc0[0], acc0[1]), pack2(acc0[2], acc0[3]),
                          pack2(acc0[4], acc0[5]), pack2(acc0[6], acc0[7]));
        o[1] = make_uint4(pack2(acc0[8], acc0[9]), pack2(acc0[10], acc0[11]),
                          pack2(acc0[12], acc0[13]), pack2(acc0[14], acc0[15]));
    }
    if (n_b < N_NODES) {
        uint4* o = (uint4*)(y + ((size_t)n_b * 256 + cbase) / 2);
        o[0] = make_uint4(pack2(acc1[0], acc1[1]), pack2(acc1[2], acc1[3]),
                          pack2(acc1[4], acc1[5]), pack2(acc1[6], acc1[7]));
        o[1] = make_uint4(pack2(acc1[8], acc1[9]), pack2(acc1[10], acc1[11]),
                          pack2(acc1[12], acc1[13]), pack2(acc1[14], acc1[15]));
    }
}

// ---- edge load/compute split for MLP ----
__device__ inline void load_edge(const uint4 r, const unsigned* __restrict__ y,
                                 int lane, uint2& q0, uint2& q1, uint2& q2, uint2& q3) {
    int sn = (int)r.x;
    const uint2* yb = (const uint2*)(y + (size_t)sn * 128);
    q0 = yb[lane];
    q1 = yb[16 + lane];
    q2 = yb[32 + lane];
    q3 = yb[48 + lane];
}

__device__ inline void compute_edge(const uint4 r, uint2 q0, uint2 q1, uint2 q2, uint2 q3,
                                    const float4 bias, float4& acc) {
    float2 e01 = unpack2(r.y);
    float2 e23 = unpack2(r.z);
    float2 a0 = unpack2(q0.x), a1 = unpack2(q0.y);
    float2 b0 = unpack2(q1.x), b1 = unpack2(q1.y);
    float2 c0 = unpack2(q2.x), c1 = unpack2(q2.y);
    float2 d0 = unpack2(q3.x), d1 = unpack2(q3.y);

    float4 z = bias;
    z.x = fmaf(e01.x, a0.x, z.x); z.y = fmaf(e01.x, a0.y, z.y);
    z.z = fmaf(e01.x, a1.x, z.z); z.w = fmaf(e01.x, a1.y, z.w);
    z.x = fmaf(e01.y, b0.x, z.x); z.y = fmaf(e01.y, b0.y, z.y);
    z.z = fmaf(e01.y, b1.x, z.z); z.w = fmaf(e01.y, b1.y, z.w);
    z.x = fmaf(e23.x, c0.x, z.x); z.y = fmaf(e23.x, c0.y, z.y);
    z.z = fmaf(e23.x, c1.x, z.z); z.w = fmaf(e23.x, c1.y, z.w);
    z.x = fmaf(e23.y, d0.x, z.x); z.y = fmaf(e23.y, d0.y, z.y);
    z.z = fmaf(e23.y, d1.x, z.z); z.w = fmaf(e23.y, d1.y, z.w);

    acc.x += fmaxf(z.x, 0.f);
    acc.y += fmaxf(z.y, 0.f);
    acc.z += fmaxf(z.z, 0.f);
    acc.w += fmaxf(z.w, 0.f);
}

// ---- aggregate core: unroll-8, batched loads ----
__device__ inline float4 agg_core(const uint4* __restrict__ rec,
                                  const int* __restrict__ start,
                                  const int* __restrict__ cnt,
                                  const unsigned* __restrict__ y,
                                  const float* __restrict__ b,
                                  int g, int lane) {
    int s0 = start[g];
    int deg = cnt[g];
    int s1 = s0 + deg;

    float4 bias = ((const float4*)b)[lane];
    float4 acc = make_float4(0.f, 0.f, 0.f, 0.f);

    int i = s0;
    for (; i + 8 <= s1; i += 8) {
        uint4 r0 = rec[i + 0];
        uint4 r1 = rec[i + 1];
        uint4 r2 = rec[i + 2];
        uint4 r3 = rec[i + 3];
        uint4 r4 = rec[i + 4];
        uint4 r5 = rec[i + 5];
        uint4 r6 = rec[i + 6];
        uint4 r7 = rec[i + 7];
        uint2 a0, a1, a2, a3, b0, b1, b2, b3, c0, c1, c2, c3, d0, d1, d2, d3;
        uint2 e0, e1, e2, e3, f0, f1, f2, f3, g0, g1, g2, g3, h0, h1, h2, h3;
        load_edge(r0, y, lane, a0, a1, a2, a3);
        load_edge(r1, y, lane, b0, b1, b2, b3);
        load_edge(r2, y, lane, c0, c1, c2, c3);
        load_edge(r3, y, lane, d0, d1, d2, d3);
        load_edge(r4, y, lane, e0, e1, e2, e3);
        load_edge(r5, y, lane, f0, f1, f2, f3);
        load_edge(r6, y, lane, g0, g1, g2, g3);
        load_edge(r7, y, lane, h0, h1, h2, h3);
        compute_edge(r0, a0, a1, a2, a3, bias, acc);
        compute_edge(r1, b0, b1, b2, b3, bias, acc);
        compute_edge(r2, c0, c1, c2, c3, bias, acc);
        compute_edge(r3, d0, d1, d2, d3, bias, acc);
        compute_edge(r4, e0, e1, e2, e3, bias, acc);
        compute_edge(r5, f0, f1, f2, f3, bias, acc);
        compute_edge(r6, g0, g1, g2, g3, bias, acc);
        compute_edge(r7, h0, h1, h2, h3, bias, acc);
    }
    if (i + 4 <= s1) {
        uint4 r0 = rec[i + 0];
        uint4 r1 = rec[i + 1];
        uint4 r2 = rec[i + 2];
        uint4 r3 = rec[i + 3];
        uint2 a0, a1, a2, a3, b0, b1, b2, b3, c0, c1, c2, c3, d0, d1, d2, d3;
        load_edge(r0, y, lane, a0, a1, a2, a3);
        load_edge(r1, y, lane, b0, b1, b2, b3);
        load_edge(r2, y, lane, c0, c1, c2, c3);
        load_edge(r3, y, lane, d0, d1, d2, d3);
        compute_edge(r0, a0, a1, a2, a3, bias, acc);
        compute_edge(r1, b0, b1, b2, b3, bias, acc);
        compute_edge(r2, c0, c1, c2, c3, bias, acc);
        compute_edge(r3, d0, d1, d2, d3, bias, acc);
        i += 4;
    }
    if (i + 2 <= s1) {
        uint4 r0 = rec[i + 0];
        uint4 r1 = rec[i + 1];
        uint2 a0, a1, a2, a3, b0, b1, b2, b3;
        load_edge(r0, y, lane, a0, a1, a2, a3);
        load_edge(r1, y, lane, b0, b1, b2, b3);
        compute_edge(r0, a0, a1, a2, a3, bias, acc);
        compute_edge(r1, b0, b1, b2, b3, bias, acc);
        i += 2;
    }
    if (i < s1) {
        uint4 r0 = rec[i];
        uint2 a0, a1, a2, a3;
        load_edge(r0, y, lane, a0, a1, a2, a3);
        compute_edge(r0, a0, a1, a2, a3, bias, acc);
    }

    float inv = 1.0f / (float)(deg > 1 ? deg : 1);
    float4 r;
    r.x = fmaxf(acc.x * inv, 0.f);
    r.y = fmaxf(acc.y * inv, 0.f);
    r.z = fmaxf(acc.z * inv, 0.f);
    r.w = fmaxf(acc.w * inv, 0.f);
    return r;
}

// ---- layer-0 aggregate ----
__global__ __launch_bounds__(256) void agg_k(const uint4* __restrict__ rec,
                                             const int* __restrict__ start,
                                             const int* __restrict__ cnt,
                                             const unsigned* __restrict__ y,
                                             const float* __restrict__ b,
                                             float* __restrict__ hout) {
    int t = blockIdx.x * 256 + threadIdx.x;
    int g = t >> 4;
    int lane = t & 15;
    float4 r = agg_core(rec, start, cnt, y, b, g, lane);
    ((float4*)hout)[(size_t)g * 16 + lane] = r;
}

// ---- layer-1 aggregate fused with final fc (block = 16 nodes) ----
__global__ __launch_bounds__(256) void agg_fc_k(const uint4* __restrict__ rec,
                                                const int* __restrict__ start,
                                                const int* __restrict__ cnt,
                                                const unsigned* __restrict__ y,
                                                const float* __restrict__ b,
                                                const float* __restrict__ Wfc,
                                                const float* __restrict__ bfc,
                                                float* __restrict__ out) {
    __shared__ float sh_h[16 * 65];
    __shared__ float sWfcT[NCLS * 65];   // transposed, padded: [c*65 + j]
    __shared__ float sbfc[NCLS];
    int t = threadIdx.x;

    for (int i = t; i < 64 * NCLS; i += 256) {
        int j = i / NCLS;
        int c = i - j * NCLS;
        sWfcT[c * 65 + j] = Wfc[i];
    }
    if (t < NCLS) sbfc[t] = bfc[t];

    int nl = t >> 4;
    int lane = t & 15;
    int g = blockIdx.x * 16 + nl;   // grid exact: 3125*16 = 50000

    float4 r = agg_core(rec, start, cnt, y, b, g, lane);
    sh_h[nl * 65 + lane * 4 + 0] = r.x;
    sh_h[nl * 65 + lane * 4 + 1] = r.y;
    sh_h[nl * 65 + lane * 4 + 2] = r.z;
    sh_h[nl * 65 + lane * 4 + 3] = r.w;
    __syncthreads();

    for (int item = t; item < 16 * NCLS; item += 256) {
        int rn = item / NCLS;
        int c = item - rn * NCLS;
        float acc = sbfc[c];
        const float* hr = &sh_h[rn * 65];
        const float* wc = &sWfcT[c * 65];
#pragma unroll
        for (int j = 0; j < 64; ++j) acc = fmaf(hr[j], wc[j], acc);
        out[(size_t)(blockIdx.x * 16 + rn) * NCLS + c] = acc;
    }
}

extern "C" void kernel_launch(void* const* d_in, const int* in_sizes, int n_in,
                              void* d_out, int out_size, void* d_ws, size_t ws_size,
                              hipStream_t stream) {
    const float* nf  = (const float*)d_in[0];
    const float* ef  = (const float*)d_in[1];
    const int*   src = (const int*)d_in[2];
    const int*   dst = (const int*)d_in[3];
    const float* W0  = (const float*)d_in[4];
    const float* b0  = (const float*)d_in[5];
    const float* W1  = (const float*)d_in[6];
    const float* b1  = (const float*)d_in[7];
    const float* Wfc = (const float*)d_in[8];
    const float* bfc = (const float*)d_in[9];
    float* out = (float*)d_out;

    char* ws = (char*)d_ws;
    size_t off = 0;
    auto alloc = [&](size_t bytes) -> void* {
        void* p = ws + off;
        off = (off + bytes + 255) & ~(size_t)255;
        return p;
    };
    int*      zbuf   = (int*)     alloc((size_t)(50176 + 512) * 4);
    int*      cnt    = zbuf;
    int*      bflag  = zbuf + 50176;
    int*      bval   = zbuf + 50176 + 256;
    int*      start  = (int*)     alloc((size_t)(N_NODES + 1) * 4);
    int*      cursor = (int*)     alloc((size_t)N_NODES * 4);
    uint4*    recA   = (uint4*)   alloc((size_t)N_EDGES * 16);
    uint4*    recB   = (uint4*)   alloc((size_t)N_EDGES * 16);
    unsigned* y      = (unsigned*)alloc((size_t)N_NODES * 256 * 2);
    float*    hbuf   = (float*)   alloc((size_t)N_NODES * 64 * 4);

    hipMemsetAsync(zbuf, 0, (size_t)(50176 + 512) * 4, stream);

    hist_k<<<EBLK, 256, 0, stream>>>(dst, cnt);
    scan_k<<<NBLK, 256, 0, stream>>>(cnt, start, cursor, bflag, bval);
    scatter_k<<<EBLK, 256, 0, stream>>>(src, dst, ef, cursor, recA, recB);

    dim3 tgrid((N_NODES + 63) / 64, 2);   // 782 x 2 (split-k)
    int agrid = N_NODES / 16;             // 3125, exact

    // layer 0
    transform_k<<<tgrid, 256, 0, stream>>>(nf, W0, y);
    agg_k<<<agrid, 256, 0, stream>>>(recA, start, cnt, y, b0, hbuf);

    // layer 1 + fused classifier
    transform_k<<<tgrid, 256, 0, stream>>>(hbuf, W1, y);
    agg_fc_k<<<agrid, 256, 0, stream>>>(recB, start, cnt, y, b1, Wfc, bfc, out);
}

// Round 4
// 306.442 us; speedup vs baseline: 2.5236x; 1.2267x over previous
//
#include <hip/hip_runtime.h>
#include <hip/hip_fp16.h>

#define N_NODES 50000
#define N_EDGES 500000
#define DIM 64
#define KDIM 4
#define HID 64
#define NCLS 40
#define NBLK ((N_NODES + 255) / 256)   // 196
#define EBLK ((N_EDGES + 255) / 256)   // 1954

__device__ inline unsigned pack2(float a, float b) {
    __half2 h = __floats2half2_rn(a, b);
    return *(unsigned*)&h;
}
__device__ inline float2 unpack2(unsigned u) {
    __half2 h = *(__half2*)&u;
    return __half22float2(h);
}

// ---- histogram of dst (in-degree) ----
__global__ void hist_k(const int* __restrict__ dst, int* __restrict__ cnt) {
    int e = blockIdx.x * 256 + threadIdx.x;
    if (e < N_EDGES) atomicAdd(&cnt[dst[e]], 1);
}

// ---- single-kernel scan: per-block scan + publish + parallel lookback ----
__global__ __launch_bounds__(256) void scan_k(const int* __restrict__ cnt,
                                              int* __restrict__ start,
                                              int* __restrict__ cursor,
                                              volatile int* __restrict__ bflag,
                                              volatile int* __restrict__ bval) {
    __shared__ int ls[256];
    __shared__ int sbase;
    __shared__ int ok_all;
    int b = blockIdx.x, t = threadIdx.x;
    int n = b * 256 + t;
    int v = (n < N_NODES) ? cnt[n] : 0;
    ls[t] = v;
    __syncthreads();
#pragma unroll
    for (int off = 1; off < 256; off <<= 1) {
        int u = (t >= off) ? ls[t - off] : 0;
        __syncthreads();
        ls[t] += u;
        __syncthreads();
    }
    int incl = ls[t];
    int total = ls[255];
    __syncthreads();

    if (t == 0) {
        bval[b] = total;
        __threadfence();
        bflag[b] = 1;
    }

    if (b > 0) {
        for (;;) {
            int f = (t < b) ? bflag[t] : 1;
            if (t == 0) ok_all = 1;
            __syncthreads();
            if (!f) ok_all = 0;
            __syncthreads();
            if (ok_all) break;
        }
        __threadfence();
        int pv = (t < b) ? bval[t] : 0;
        ls[t] = pv;
        __syncthreads();
#pragma unroll
        for (int off = 128; off > 0; off >>= 1) {
            if (t < off) ls[t] += ls[t + off];
            __syncthreads();
        }
        if (t == 0) sbase = ls[0];
        __syncthreads();
    } else {
        if (t == 0) sbase = 0;
        __syncthreads();
    }

    int excl = sbase + incl - v;
    if (n < N_NODES) { start[n] = excl; cursor[n] = excl; }
    if (n == 0) start[N_NODES] = N_EDGES;
}

// ---- counting-sort scatter: write ONLY recA (16B random store/edge),
//      keep edge index in .w so recB can be built by a streaming repack ----
__global__ void scatter_k(const int* __restrict__ src, const int* __restrict__ dst,
                          const float* __restrict__ ef, int* __restrict__ cursor,
                          uint4* __restrict__ recA) {
    int e = blockIdx.x * 256 + threadIdx.x;
    if (e < N_EDGES) {
        int d = dst[e];
        int pos = atomicAdd(&cursor[d], 1);
        int sn = src[e];
        float4 f0 = ((const float4*)ef)[e];
        recA[pos] = make_uint4((unsigned)sn, pack2(f0.x, f0.y), pack2(f0.z, f0.w), (unsigned)e);
    }
}

// ---- streaming repack: build layer-1 records from recA order ----
// streaming read recA (8MB) + cached gather ef1 (8MB, L2/L3-resident) + streaming write recB (8MB)
__global__ void repack_k(const uint4* __restrict__ recA, const float* __restrict__ ef1,
                         uint4* __restrict__ recB) {
    int i = blockIdx.x * 256 + threadIdx.x;
    if (i < N_EDGES) {
        uint4 r = recA[i];
        int e = (int)r.w;
        float4 f1 = ((const float4*)ef1)[e];
        recB[i] = make_uint4(r.x, pack2(f1.x, f1.y), pack2(f1.z, f1.w), 0u);
    }
}

// ---- node transform, split-k: blockIdx.y = kpair (k in {2*kpair, 2*kpair+1}) ----
// 64 nodes/block, 32KB W-slice + 16.6KB h-tile = 48.9KB LDS -> 3 blocks/CU
__global__ __launch_bounds__(256) void transform_k(const float* __restrict__ hin,
                                                   const float* __restrict__ W,
                                                   unsigned* __restrict__ y) {
    __shared__ float sW[2 * 64 * 64];      // 32 KB: two k-slices
    __shared__ float sh[64 * 65];          // 16.6 KB
    int t = threadIdx.x;
    int kpair = blockIdx.y;

    // stage W slice: 8192 floats = 2048 float4 / 256 threads = 8 each
    const float4* W4 = (const float4*)(W + (size_t)kpair * 2 * 4096);
    float4* sW4 = (float4*)sW;
#pragma unroll
    for (int i = 0; i < 8; ++i) sW4[t + 256 * i] = W4[t + 256 * i];

    int n0 = blockIdx.x * 64;
    // stage h tile: 64 nodes x 16 float4 = 1024 float4 -> 4 per thread
#pragma unroll
    for (int i = 0; i < 4; ++i) {
        int idx = t + 256 * i;        // 0..1023
        int nl = idx >> 4;            // 0..63
        int dg = idx & 15;
        int n = n0 + nl;
        float4 v = make_float4(0.f, 0.f, 0.f, 0.f);
        if (n < N_NODES) v = ((const float4*)hin)[(size_t)n * 16 + dg];
        sh[nl * 65 + dg * 4 + 0] = v.x;
        sh[nl * 65 + dg * 4 + 1] = v.y;
        sh[nl * 65 + dg * 4 + 2] = v.z;
        sh[nl * 65 + dg * 4 + 3] = v.w;
    }
    __syncthreads();

    // 256 threads = 8 col-groups (16 cols each over the 128 cols of this kpair)
    // x 32 node-slots; each slot handles nodes nl and nl+32
    int nl = t & 31;
    int cg = t >> 5;                  // 0..7
    int k_local = cg >> 2;            // 0..1
    int hc0 = (cg & 3) * 16;

    float acc0[16], acc1[16];
#pragma unroll
    for (int j = 0; j < 16; ++j) { acc0[j] = 0.f; acc1[j] = 0.f; }

    for (int d = 0; d < 64; ++d) {
        float a0 = sh[nl * 65 + d];
        float a1 = sh[(nl + 32) * 65 + d];
        const float* wr = &sW[k_local * 4096 + d * 64 + hc0];
#pragma unroll
        for (int j = 0; j < 16; ++j) {
            float w = wr[j];
            acc0[j] = fmaf(a0, w, acc0[j]);
            acc1[j] = fmaf(a1, w, acc1[j]);
        }
    }

    int n_a = n0 + nl, n_b = n0 + nl + 32;
    int cbase = (kpair * 2 + k_local) * 64 + hc0;
    if (n_a < N_NODES) {
        uint4* o = (uint4*)(y + ((size_t)n_a * 256 + cbase) / 2);
        o[0] = make_uint4(pack2(acc0[0], acc0[1]), pack2(acc0[2], acc0[3]),
                          pack2(acc0[4], acc0[5]), pack2(acc0[6], acc0[7]));
        o[1] = make_uint4(pack2(acc0[8], acc0[9]), pack2(acc0[10], acc0[11]),
                          pack2(acc0[12], acc0[13]), pack2(acc0[14], acc0[15]));
    }
    if (n_b < N_NODES) {
        uint4* o = (uint4*)(y + ((size_t)n_b * 256 + cbase) / 2);
        o[0] = make_uint4(pack2(acc1[0], acc1[1]), pack2(acc1[2], acc1[3]),
                          pack2(acc1[4], acc1[5]), pack2(acc1[6], acc1[7]));
        o[1] = make_uint4(pack2(acc1[8], acc1[9]), pack2(acc1[10], acc1[11]),
                          pack2(acc1[12], acc1[13]), pack2(acc1[14], acc1[15]));
    }
}

// ---- edge load/compute split for MLP ----
__device__ inline void load_edge(const uint4 r, const unsigned* __restrict__ y,
                                 int lane, uint2& q0, uint2& q1, uint2& q2, uint2& q3) {
    int sn = (int)r.x;
    const uint2* yb = (const uint2*)(y + (size_t)sn * 128);
    q0 = yb[lane];
    q1 = yb[16 + lane];
    q2 = yb[32 + lane];
    q3 = yb[48 + lane];
}

__device__ inline void compute_edge(const uint4 r, uint2 q0, uint2 q1, uint2 q2, uint2 q3,
                                    const float4 bias, float4& acc) {
    float2 e01 = unpack2(r.y);
    float2 e23 = unpack2(r.z);
    float2 a0 = unpack2(q0.x), a1 = unpack2(q0.y);
    float2 b0 = unpack2(q1.x), b1 = unpack2(q1.y);
    float2 c0 = unpack2(q2.x), c1 = unpack2(q2.y);
    float2 d0 = unpack2(q3.x), d1 = unpack2(q3.y);

    float4 z = bias;
    z.x = fmaf(e01.x, a0.x, z.x); z.y = fmaf(e01.x, a0.y, z.y);
    z.z = fmaf(e01.x, a1.x, z.z); z.w = fmaf(e01.x, a1.y, z.w);
    z.x = fmaf(e01.y, b0.x, z.x); z.y = fmaf(e01.y, b0.y, z.y);
    z.z = fmaf(e01.y, b1.x, z.z); z.w = fmaf(e01.y, b1.y, z.w);
    z.x = fmaf(e23.x, c0.x, z.x); z.y = fmaf(e23.x, c0.y, z.y);
    z.z = fmaf(e23.x, c1.x, z.z); z.w = fmaf(e23.x, c1.y, z.w);
    z.x = fmaf(e23.y, d0.x, z.x); z.y = fmaf(e23.y, d0.y, z.y);
    z.z = fmaf(e23.y, d1.x, z.z); z.w = fmaf(e23.y, d1.y, z.w);

    acc.x += fmaxf(z.x, 0.f);
    acc.y += fmaxf(z.y, 0.f);
    acc.z += fmaxf(z.z, 0.f);
    acc.w += fmaxf(z.w, 0.f);
}

// ---- aggregate core: unroll-4, batched loads (round-0 schedule, contiguous rec) ----
__device__ inline float4 agg_core(const uint4* __restrict__ rec,
                                  const int* __restrict__ start,
                                  const int* __restrict__ cnt,
                                  const unsigned* __restrict__ y,
                                  const float* __restrict__ b,
                                  int g, int lane) {
    int s0 = start[g];
    int deg = cnt[g];
    int s1 = s0 + deg;

    float4 bias = ((const float4*)b)[lane];
    float4 acc = make_float4(0.f, 0.f, 0.f, 0.f);

    int i = s0;
    for (; i + 4 <= s1; i += 4) {
        uint4 r0 = rec[i + 0];
        uint4 r1 = rec[i + 1];
        uint4 r2 = rec[i + 2];
        uint4 r3 = rec[i + 3];
        uint2 a0, a1, a2, a3, b0, b1, b2, b3, c0, c1, c2, c3, d0, d1, d2, d3;
        load_edge(r0, y, lane, a0, a1, a2, a3);
        load_edge(r1, y, lane, b0, b1, b2, b3);
        load_edge(r2, y, lane, c0, c1, c2, c3);
        load_edge(r3, y, lane, d0, d1, d2, d3);
        compute_edge(r0, a0, a1, a2, a3, bias, acc);
        compute_edge(r1, b0, b1, b2, b3, bias, acc);
        compute_edge(r2, c0, c1, c2, c3, bias, acc);
        compute_edge(r3, d0, d1, d2, d3, bias, acc);
    }
    if (i + 2 <= s1) {
        uint4 r0 = rec[i + 0];
        uint4 r1 = rec[i + 1];
        uint2 a0, a1, a2, a3, b0, b1, b2, b3;
        load_edge(r0, y, lane, a0, a1, a2, a3);
        load_edge(r1, y, lane, b0, b1, b2, b3);
        compute_edge(r0, a0, a1, a2, a3, bias, acc);
        compute_edge(r1, b0, b1, b2, b3, bias, acc);
        i += 2;
    }
    if (i < s1) {
        uint4 r0 = rec[i];
        uint2 a0, a1, a2, a3;
        load_edge(r0, y, lane, a0, a1, a2, a3);
        compute_edge(r0, a0, a1, a2, a3, bias, acc);
    }

    float inv = 1.0f / (float)(deg > 1 ? deg : 1);
    float4 r;
    r.x = fmaxf(acc.x * inv, 0.f);
    r.y = fmaxf(acc.y * inv, 0.f);
    r.z = fmaxf(acc.z * inv, 0.f);
    r.w = fmaxf(acc.w * inv, 0.f);
    return r;
}

// ---- layer-0 aggregate ----
__global__ __launch_bounds__(256) void agg_k(const uint4* __restrict__ rec,
                                             const int* __restrict__ start,
                                             const int* __restrict__ cnt,
                                             const unsigned* __restrict__ y,
                                             const float* __restrict__ b,
                                             float* __restrict__ hout) {
    int t = blockIdx.x * 256 + threadIdx.x;
    int g = t >> 4;
    int lane = t & 15;
    float4 r = agg_core(rec, start, cnt, y, b, g, lane);
    ((float4*)hout)[(size_t)g * 16 + lane] = r;
}

// ---- layer-1 aggregate fused with final fc (block = 16 nodes) ----
__global__ __launch_bounds__(256) void agg_fc_k(const uint4* __restrict__ rec,
                                                const int* __restrict__ start,
                                                const int* __restrict__ cnt,
                                                const unsigned* __restrict__ y,
                                                const float* __restrict__ b,
                                                const float* __restrict__ Wfc,
                                                const float* __restrict__ bfc,
                                                float* __restrict__ out) {
    __shared__ float sh_h[16 * 65];
    __shared__ float sWfcT[NCLS * 65];   // transposed, padded: [c*65 + j]
    __shared__ float sbfc[NCLS];
    int t = threadIdx.x;

    for (int i = t; i < 64 * NCLS; i += 256) {
        int j = i / NCLS;
        int c = i - j * NCLS;
        sWfcT[c * 65 + j] = Wfc[i];
    }
    if (t < NCLS) sbfc[t] = bfc[t];

    int nl = t >> 4;
    int lane = t & 15;
    int g = blockIdx.x * 16 + nl;   // grid exact: 3125*16 = 50000

    float4 r = agg_core(rec, start, cnt, y, b, g, lane);
    sh_h[nl * 65 + lane * 4 + 0] = r.x;
    sh_h[nl * 65 + lane * 4 + 1] = r.y;
    sh_h[nl * 65 + lane * 4 + 2] = r.z;
    sh_h[nl * 65 + lane * 4 + 3] = r.w;
    __syncthreads();

    for (int item = t; item < 16 * NCLS; item += 256) {
        int rn = item / NCLS;
        int c = item - rn * NCLS;
        float acc = sbfc[c];
        const float* hr = &sh_h[rn * 65];
        const float* wc = &sWfcT[c * 65];
#pragma unroll
        for (int j = 0; j < 64; ++j) acc = fmaf(hr[j], wc[j], acc);
        out[(size_t)(blockIdx.x * 16 + rn) * NCLS + c] = acc;
    }
}

extern "C" void kernel_launch(void* const* d_in, const int* in_sizes, int n_in,
                              void* d_out, int out_size, void* d_ws, size_t ws_size,
                              hipStream_t stream) {
    const float* nf  = (const float*)d_in[0];
    const float* ef  = (const float*)d_in[1];
    const int*   src = (const int*)d_in[2];
    const int*   dst = (const int*)d_in[3];
    const float* W0  = (const float*)d_in[4];
    const float* b0  = (const float*)d_in[5];
    const float* W1  = (const float*)d_in[6];
    const float* b1  = (const float*)d_in[7];
    const float* Wfc = (const float*)d_in[8];
    const float* bfc = (const float*)d_in[9];
    float* out = (float*)d_out;

    char* ws = (char*)d_ws;
    size_t off = 0;
    auto alloc = [&](size_t bytes) -> void* {
        void* p = ws + off;
        off = (off + bytes + 255) & ~(size_t)255;
        return p;
    };
    int*      zbuf   = (int*)     alloc((size_t)(50176 + 512) * 4);
    int*      cnt    = zbuf;
    int*      bflag  = zbuf + 50176;
    int*      bval   = zbuf + 50176 + 256;
    int*      start  = (int*)     alloc((size_t)(N_NODES + 1) * 4);
    int*      cursor = (int*)     alloc((size_t)N_NODES * 4);
    uint4*    recA   = (uint4*)   alloc((size_t)N_EDGES * 16);
    uint4*    recB   = (uint4*)   alloc((size_t)N_EDGES * 16);
    unsigned* y      = (unsigned*)alloc((size_t)N_NODES * 256 * 2);
    float*    hbuf   = (float*)   alloc((size_t)N_NODES * 64 * 4);

    hipMemsetAsync(zbuf, 0, (size_t)(50176 + 512) * 4, stream);

    hist_k<<<EBLK, 256, 0, stream>>>(dst, cnt);
    scan_k<<<NBLK, 256, 0, stream>>>(cnt, start, cursor, bflag, bval);
    scatter_k<<<EBLK, 256, 0, stream>>>(src, dst, ef, cursor, recA);
    repack_k<<<EBLK, 256, 0, stream>>>(recA, ef + (size_t)N_EDGES * 4, recB);

    dim3 tgrid((N_NODES + 63) / 64, 2);   // 782 x 2 (split-k)
    int agrid = N_NODES / 16;             // 3125, exact

    // layer 0
    transform_k<<<tgrid, 256, 0, stream>>>(nf, W0, y);
    agg_k<<<agrid, 256, 0, stream>>>(recA, start, cnt, y, b0, hbuf);

    // layer 1 + fused classifier
    transform_k<<<tgrid, 256, 0, stream>>>(hbuf, W1, y);
    agg_fc_k<<<agrid, 256, 0, stream>>>(recB, start, cnt, y, b1, Wfc, bfc, out);
}